// Round 11
// baseline (181.214 us; speedup 1.0000x reference)
//
#include <hip/hip_runtime.h>

typedef unsigned short u16;
typedef unsigned int u32;
typedef __bf16 bf16x8 __attribute__((ext_vector_type(8)));
typedef float f32x4 __attribute__((ext_vector_type(4)));

#define DEV __device__ __forceinline__

// Problem constants (B,T,D_MODEL,H) = (2,2048,1024,16)
constexpr int BB = 2;
constexpr int TT = 2048;
constexpr int CD = 1024;
constexpr int HH = 16;
constexpr int DH = 64;
constexpr int BT = BB * TT;   // 4096

// softmax scale 1/8 folded with log2(e): S' = S/8*log2e, exp(x)=exp2(x')
#define QSCALE 0.18033688011112042f

// Native bf16 convert (RTNE): compiler packs pairs into v_cvt_pk_bf16_f32.
DEV u16 f2bf(float f) {
    return __builtin_bit_cast(u16, (__bf16)f);
}

DEV f32x4 mfma16(bf16x8 a, bf16x8 b, f32x4 c) {
    return __builtin_amdgcn_mfma_f32_16x16x32_bf16(a, b, c, 0, 0, 0);
}

// Async global->LDS, 16B per lane: LDS dest = wave-uniform base + lane*16.
DEV void gld_lds16(u16* lds, const u16* g) {
    __builtin_amdgcn_global_load_lds(
        (const __attribute__((address_space(1))) unsigned int*)g,
        (__attribute__((address_space(3))) unsigned int*)lds, 16, 0, 0);
}

// ---------------------------------------------------------------------------
// Fused preprocessing (single launch):
//   blocks [0,2048):      x fp32 -> bf16 (4096x1024), uint4-vectorized
//   blocks [2048,2816):   W_qkv (1024x3072) -> transposed bf16, 64x64 tiles
//   blocks [2816,3072):   W_o   (1024x1024) -> transposed bf16, 64x64 tiles
// ---------------------------------------------------------------------------
__global__ __launch_bounds__(256)
void prep_kernel(const float* __restrict__ x, u16* __restrict__ xb,
                 const float* __restrict__ Wqkv, u16* __restrict__ WqkvT,
                 const float* __restrict__ Wo, u16* __restrict__ WoT) {
    const int tid = threadIdx.x;
    int blk = blockIdx.x;
    if (blk < 2048) {                       // convert job
        const int i = (blk * 256 + tid) * 8;
        float4 a = *(const float4*)&x[i];
        float4 b = *(const float4*)&x[i + 4];
        u16 t[8];
        t[0] = f2bf(a.x); t[1] = f2bf(a.y); t[2] = f2bf(a.z); t[3] = f2bf(a.w);
        t[4] = f2bf(b.x); t[5] = f2bf(b.y); t[6] = f2bf(b.z); t[7] = f2bf(b.w);
        *(uint4*)&xb[i] = *(const uint4*)t;
        return;                             // whole block exits (no barrier)
    }
    __shared__ u16 tile[64][72];            // [col][row], padded stride
    const float* in; u16* out; int rows, cols, bx, by;
    blk -= 2048;
    if (blk < 768) { in = Wqkv; out = WqkvT; rows = 1024; cols = 3072; bx = blk % 48; by = blk / 48; }
    else { blk -= 768; in = Wo; out = WoT; rows = 1024; cols = 1024; bx = blk % 16; by = blk / 16; }
    const int c0 = bx * 64, r0 = by * 64;

    // read: 16 rows x 16 float4-groups per pass, 4 passes
    const int tx = tid & 15, ty = tid >> 4;
    #pragma unroll
    for (int p = 0; p < 4; ++p) {
        const int r = ty + p * 16;
        float4 v = *(const float4*)&in[(size_t)(r0 + r) * cols + c0 + tx * 4];
        tile[tx * 4 + 0][r] = f2bf(v.x);
        tile[tx * 4 + 1][r] = f2bf(v.y);
        tile[tx * 4 + 2][r] = f2bf(v.z);
        tile[tx * 4 + 3][r] = f2bf(v.w);
    }
    __syncthreads();

    // write: thread -> out-row c0+(tid>>2), 16 consecutive r at (tid&3)*16
    const int c = tid >> 2, r8 = (tid & 3) * 16;
    u16* dst = &out[(size_t)(c0 + c) * rows + r0 + r8];
    *(uint4*)dst       = *(const uint4*)&tile[c][r8];
    *(uint4*)(dst + 8) = *(const uint4*)&tile[c][r8 + 8];
}

// ---------------------------------------------------------------------------
// GEMM v4: 3-deep pipelined staging + counted vmcnt (T4) + chunk-XOR LDS
// swizzle (T2).  C[M][N] = A[M][K] * Bt[N][K]^T, bf16->fp32 acc.
// QKV = 128x128 (768 blocks, 3/CU); out-proj = 64x64 (1024 blocks, 4/CU).
// T1 XCD-chunked block swizzle.  (Unchanged from round 9/10.)
// ---------------------------------------------------------------------------
template <int EPI, int BM, int BN, int GX>
__global__ __launch_bounds__(256)
void gemm_db(const u16* __restrict__ A, const u16* __restrict__ Bt,
             u16* __restrict__ out0, u16* __restrict__ out1,
             u16* __restrict__ out2, float* __restrict__ outf,
             int M, int N, int K) {
    constexpr int BK = 32, AST = 32;
    constexpr int MT = BM / 32;             // m-tiles per wave
    constexpr int NT = BN / 32;             // n-tiles per wave
    constexpr int MBLK = 4096 / BM;         // M = 4096 always here
    constexpr int NBLK = GX * MBLK;
    constexpr int CPX = NBLK / 8;           // blocks per XCD chunk
    constexpr int LPS = BM / 64 + BN / 64;  // gld_lds per stage per wave
    __shared__ alignas(16) u16 As[3][BM * AST];
    __shared__ alignas(16) u16 Bs[3][BN * AST];

    const int tid  = threadIdx.x;
    const int wave = tid >> 6, lane = tid & 63;
    const int quad = lane >> 4, l16 = lane & 15;
    const int wm = (wave & 1) * (BM / 2), wn = (wave >> 1) * (BN / 2);

    // T1: XCD-aware chunked swizzle (bijective since NBLK % 8 == 0)
    int bid = (int)blockIdx.x;
    bid = (bid & 7) * CPX + (bid >> 3);
    const int bx = bid % GX, by = bid / GX;
    const int m0 = by * BM, n0 = bx * BN;

    // DMA staging: one instr = 64 lanes x 16B = 16 rows x 64B.
    // T2 pre-swizzled global source chunk (stored[r][c]=logical[c^((r>>1)&3)]).
    const int srowA = wave * (BM / 4) + (lane >> 2);
    const int srowB = wave * (BN / 4) + (lane >> 2);
    const int scol  = (((lane & 3) ^ ((lane >> 3) & 3))) * 8;
    const u16* ga0 = A  + (size_t)(m0 + srowA) * K + scol;
    const u16* ga1 = ga0 + (size_t)16 * K;
    const u16* gb0 = Bt + (size_t)(n0 + srowB) * K + scol;
    const u16* gb1 = gb0 + (size_t)16 * K;

    auto stage = [&](int buf, int k0) {
        gld_lds16(&As[buf][wave * (BM / 4) * 32],       ga0 + k0);
        if constexpr (BM == 128)
            gld_lds16(&As[buf][wave * (BM / 4) * 32 + 512], ga1 + k0);
        gld_lds16(&Bs[buf][wave * (BN / 4) * 32],       gb0 + k0);
        if constexpr (BN == 128)
            gld_lds16(&Bs[buf][wave * (BN / 4) * 32 + 512], gb1 + k0);
    };
    // mid-loop counted wait: one stage (LPS loads) stays in flight
    auto wait_lps = [&]() {
        if constexpr (LPS == 4)      asm volatile("s_waitcnt vmcnt(4)" ::: "memory");
        else if constexpr (LPS == 3) asm volatile("s_waitcnt vmcnt(3)" ::: "memory");
        else                         asm volatile("s_waitcnt vmcnt(2)" ::: "memory");
    };

    f32x4 acc[MT][NT] = {};

    stage(0, 0);
    stage(1, BK);
    wait_lps();                              // step-0 buffers landed
    __builtin_amdgcn_s_barrier();

    const int sx = ((l16 >> 1) & 3) * 8;     // T2 read-side XOR term
    const int NS = K / BK;
    int cb = 0;                              // current buffer
    for (int t = 0; t < NS; ++t) {
        const bool pf = (t + 2 < NS);
        int sb = cb + 2; if (sb >= 3) sb -= 3;
        if (pf) stage(sb, (t + 2) * BK);

        bf16x8 fa[MT], fb[NT];
        #pragma unroll
        for (int mt = 0; mt < MT; ++mt)
            fa[mt] = *(const bf16x8*)
                &As[cb][(wm + mt * 16 + l16) * AST + (quad * 8 ^ sx)];
        #pragma unroll
        for (int nt = 0; nt < NT; ++nt)
            fb[nt] = *(const bf16x8*)
                &Bs[cb][(wn + nt * 16 + l16) * AST + (quad * 8 ^ sx)];
        #pragma unroll
        for (int mt = 0; mt < MT; ++mt)
            #pragma unroll
            for (int nt = 0; nt < NT; ++nt)
                acc[mt][nt] = mfma16(fa[mt], fb[nt], acc[mt][nt]);

        if (pf) wait_lps();                  // drain stage for step t+1 only
        else    asm volatile("s_waitcnt vmcnt(0)" ::: "memory");
        __builtin_amdgcn_s_barrier();
        cb = (cb + 1 == 3) ? 0 : cb + 1;
    }

    // Epilogue. C/D layout: row = quad*4+reg, col = l16.
    #pragma unroll
    for (int mt = 0; mt < MT; ++mt) {
        #pragma unroll
        for (int nt = 0; nt < NT; ++nt) {
            #pragma unroll
            for (int reg = 0; reg < 4; ++reg) {
                const int r = m0 + wm + mt * 16 + quad * 4 + reg;
                const int c = n0 + wn + nt * 16 + l16;
                if (EPI == 0) {
                    outf[(size_t)r * N + c] = acc[mt][nt][reg];
                } else {
                    const int which = c >> 10;       // 0=q 1=k 2=v
                    const int cc = c & 1023;
                    const int h = cc >> 6, d = cc & 63;
                    const int b = r >> 11, t = r & 2047;
                    const int bh = b * HH + h;
                    if (which == 0) {
                        out0[((size_t)bh * TT + t) * DH + d] =
                            f2bf(acc[mt][nt][reg] * QSCALE);
                    } else if (which == 1) {
                        out1[((size_t)bh * TT + t) * DH + d] = f2bf(acc[mt][nt][reg]);
                    } else {
                        out2[((size_t)bh * DH + d) * TT + t] = f2bf(acc[mt][nt][reg]);
                    }
                }
            }
        }
    }
}

// ---------------------------------------------------------------------------
// Flash attention v9 (causal): latency-bound fix -- MORE independent convoys.
// 2048 blocks x 2 waves (32 q-rows each), single-buffered LDS 17.4 KB:
//   K: 8 KB, staged via global_load_lds with pre-swizzled source (T2
//      both-sides: stored[r][c] = logical[c ^ (r&7)]) -> conflict-free
//      ds_read_b128 fragments;
//   V: 9.2 KB (KST=72), reg-staged pair-permuted (unchanged layout).
// __launch_bounds__(128,4) caps VGPR at 128 -> 8 blocks/CU = 16 waves in
// 8 independent convoys (vs 4x4-wave barrier groups).  Rationale: attn
// counters (r2) showed MfmaUtil 13 / VALU 35 / Occ 16 -- both pipes low +
// low occupancy = latency-bound; the fix is concurrency, not algorithm.
// Keeps v8's ones-row l-accumulation + defer-max (measured win) and
// longest-qt-first dispatch + bh%8==XCD L2 locality.
// Schedule/step: syncA (K-dma vmcnt drained, V writes visible) ->
//   vload(j+1) -> compute(j) -> syncB (LDS reads done) ->
//   kdma(j+1) + vwrite(j+1).
// ---------------------------------------------------------------------------
constexpr int KST = 72;  // V LDS row stride (144 B, rows 16B-aligned)

DEV void attn_step(const bf16x8 fk[4][2], const bf16x8 fv[2][4],
                   const bf16x8 fone, const bf16x8* fq,
                   f32x4* Oacc, f32x4& lacc, float& m_i, bool diag,
                   int qg, int quad) {
    // S^T: 4 key-tiles x 2 k-steps over d
    f32x4 st[4];
    #pragma unroll
    for (int nt = 0; nt < 4; ++nt) {
        f32x4 t = {};
        t = mfma16(fk[nt][0], fq[0], t);   // A=K (m=key), B=Q (n=q)
        t = mfma16(fk[nt][1], fq[1], t);
        st[nt] = t;
    }

    // causal mask on diagonal tile: key_loc <= q_loc
    if (diag) {
        #pragma unroll
        for (int nt = 0; nt < 4; ++nt)
            #pragma unroll
            for (int reg = 0; reg < 4; ++reg) {
                const int kg = nt * 16 + quad * 4 + reg;
                st[nt][reg] = (kg <= qg) ? st[nt][reg] : -INFINITY;
            }
    }

    // row max: depth-4 tree + 2 cross-quad shuffles (lane = quad*16+l16)
    float v[16];
    #pragma unroll
    for (int nt = 0; nt < 4; ++nt)
        #pragma unroll
        for (int reg = 0; reg < 4; ++reg)
            v[nt * 4 + reg] = st[nt][reg];
    #pragma unroll
    for (int s = 8; s > 0; s >>= 1)
        #pragma unroll
        for (int i = 0; i < s; ++i)
            v[i] = fmaxf(v[i], v[i + s]);
    float vmax = v[0];
    vmax = fmaxf(vmax, __shfl_xor(vmax, 16, 64));
    vmax = fmaxf(vmax, __shfl_xor(vmax, 32, 64));

    // defer-max: rescale only when some row's max grew past THR=8 (exp2 dom)
    if (!__all(vmax - m_i <= 8.f)) {
        const float mnew = fmaxf(m_i, vmax);
        const float alpha = __builtin_amdgcn_exp2f(m_i - mnew);
        m_i = mnew;
        #pragma unroll
        for (int dt = 0; dt < 4; ++dt)
            #pragma unroll
            for (int reg = 0; reg < 4; ++reg)
                Oacc[dt][reg] *= alpha;
        #pragma unroll
        for (int reg = 0; reg < 4; ++reg)
            lacc[reg] *= alpha;
    }

    #pragma unroll
    for (int nt = 0; nt < 4; ++nt)
        #pragma unroll
        for (int reg = 0; reg < 4; ++reg)
            st[nt][reg] = __builtin_amdgcn_exp2f(st[nt][reg] - m_i);

    // P^T B-operand: reg j<4 = st[2p][j] (key p*32+quad*4+j),
    //                reg j>=4 = st[2p+1][j-4] (key p*32+16+quad*4+j-4)
    // ones-row MFMA accumulates sum(P) into lacc (C row 0 = quad0/reg0).
    #pragma unroll
    for (int pair = 0; pair < 2; ++pair) {
        bf16x8 pb;
        #pragma unroll
        for (int j = 0; j < 4; ++j) {
            pb[j]     = (__bf16)st[2 * pair][j];
            pb[4 + j] = (__bf16)st[2 * pair + 1][j];
        }
        lacc = mfma16(fone, pb, lacc);
        #pragma unroll
        for (int dt = 0; dt < 4; ++dt)
            Oacc[dt] = mfma16(fv[pair][dt], pb, Oacc[dt]);
    }
}

__global__ __launch_bounds__(128, 4)
void attn_kernel(const u16* __restrict__ Q, const u16* __restrict__ Kb,
                 const u16* __restrict__ Vt, u16* __restrict__ O) {
    __shared__ alignas(16) u16 Ks[64 * 64];      // K, chunk-XOR swizzled
    __shared__ alignas(16) u16 Vs[64 * KST];     // V, pair-permuted

    // Decode: bid[2:0] = XCD (bh%8), bid[4:0] = bh, bid[10:5] = task
    // (longest q-tile first; task = (31-qt)*2 + half).
    const int bid = (int)blockIdx.x;
    const int bh = bid & 31;
    const int t6 = bid >> 5;                 // 0..63
    const int qt = 31 - (t6 >> 1);
    const int half = t6 & 1;
    const int jmax = qt;

    const int tid = threadIdx.x;             // 0..127
    const int wave = tid >> 6, lane = tid & 63;
    const int quad = lane >> 4, l16 = lane & 15;

    const u16* Qh = Q  + (size_t)bh * TT * DH;
    const u16* Kh = Kb + (size_t)bh * TT * DH;
    const u16* Vh = Vt + (size_t)bh * DH * TT;

    const int row = qt * 64 + half * 32 + wave * 16;
    const int qg  = half * 32 + wave * 16 + l16;   // q pos within 64-key tile

    // Q fragments (B-operand: n = l16 = q, k = quad*8+j over d)
    bf16x8 fq[2];
    fq[0] = *(const bf16x8*)&Qh[(row + l16) * DH + quad * 8];
    fq[1] = *(const bf16x8*)&Qh[(row + l16) * DH + 32 + quad * 8];

    // ones A-fragment: lanes with l16==0 hold the all-ones row 0.
    bf16x8 fone;
    {
        const __bf16 ov = (l16 == 0) ? (__bf16)1.f : (__bf16)0.f;
        #pragma unroll
        for (int j = 0; j < 8; ++j) fone[j] = ov;
    }

    f32x4 Oa[4] = {}, lacc = {};
    float m_i = -INFINITY;

    // K DMA: per wave 4x gld_lds, each covers 8 rows x 128 B.  Pre-swizzled
    // global source: lane l fetches logical chunk (l&7)^(l>>3) of its row,
    // so stored[r][c] = logical[c ^ (r&7)]  (r&7 == l>>3; bases = 0 mod 8).
    const int krow8  = lane >> 3;                       // 0..7
    const int kchunk = ((lane & 7) ^ krow8) * 8;
    const u16* gK = Kh + (size_t)(wave * 32 + krow8) * DH + kchunk;
    auto kdma = [&](int j) {
        const u16* g = gK + (size_t)j * 64 * DH;
        #pragma unroll
        for (int i = 0; i < 4; ++i)
            gld_lds16(&Ks[(wave * 32 + i * 8) * 64], g + (size_t)i * 8 * DH);
    };

    // V staging: 128 threads x 4 rows x 16 B (pair-permuted columns).
    const int trow = tid >> 3;               // 0..15
    const int ic   = tid & 7;                // 8-key group index
    const int tcol = ic * 8;
    const int vc1 = 32 * (ic >> 2) + 16 * (ic & 1) + 4 * ((ic & 3) >> 1);
    uint4 vr[4];

    auto vload = [&](int j) {
        const u16* vs = Vh + (size_t)j * 64;
        #pragma unroll
        for (int k = 0; k < 4; ++k)
            vr[k] = *(const uint4*)&vs[(size_t)(trow + 16 * k) * TT + tcol];
    };
    auto vwrite = [&]() {
        #pragma unroll
        for (int k = 0; k < 4; ++k) {
            *(uint2*)&Vs[(trow + 16 * k) * KST + vc1]     = *(const uint2*)&vr[k];
            *(uint2*)&Vs[(trow + 16 * k) * KST + vc1 + 8] = *((const uint2*)&vr[k] + 1);
        }
    };

    vload(0);
    kdma(0);
    vwrite();                                // waits vr via data dep

    for (int j = 0; j <= jmax; ++j) {
        __syncthreads();                     // K dma landed (vmcnt), V visible
        if (j < jmax) vload(j + 1);          // V loads fly during compute

        // K fragments: logical chunk ks*4+quad at row r -> phys ^ (l16&7)
        bf16x8 fk[4][2], fv[2][4];
        #pragma unroll
        for (int nt = 0; nt < 4; ++nt)
            #pragma unroll
            for (int ks = 0; ks < 2; ++ks)
                fk[nt][ks] = *(const bf16x8*)
                    &Ks[(nt * 16 + l16) * 64 + (((ks * 4 + quad) ^ (l16 & 7)) << 3)];
        #pragma unroll
        for (int pair = 0; pair < 2; ++pair)
            #pragma unroll
            for (int dt = 0; dt < 4; ++dt)
                fv[pair][dt] = *(const bf16x8*)
                    &Vs[(dt * 16 + l16) * KST + pair * 32 + quad * 8];

        attn_step(fk, fv, fone, fq, Oa, lacc, m_i, (j == qt), qg, quad);

        __syncthreads();                     // all LDS reads of chunk j done
        if (j < jmax) { kdma(j + 1); vwrite(); }
    }

    // l for this lane's q-col lives in the quad-0 lane of the same column.
    const float lrow = __shfl(lacc[0], l16, 64);
    const float r_i = 1.f / lrow;

    // Epilogue: O^T rows d = dt*16+quad*4+reg, col q = l16; write (B,T,C).
    const int b = bh >> 4, h = bh & 15;
    #pragma unroll
    for (int dt = 0; dt < 4; ++dt) {
        u16 oa[4];
        #pragma unroll
        for (int reg = 0; reg < 4; ++reg)
            oa[reg] = f2bf(Oa[dt][reg] * r_i);
        *(uint2*)&O[((size_t)(b * TT + row + l16)) * CD + h * DH + dt * 16 + quad * 4] =
            *(const uint2*)oa;
    }
}

// ---------------------------------------------------------------------------
extern "C" void kernel_launch(void* const* d_in, const int* in_sizes, int n_in,
                              void* d_out, int out_size, void* d_ws, size_t ws_size,
                              hipStream_t stream) {
    (void)in_sizes; (void)n_in; (void)out_size; (void)ws_size;
    const float* x    = (const float*)d_in[0];   // (4096, 1024) fp32
    const float* Wqkv = (const float*)d_in[1];   // (1024, 3072) fp32
    const float* Wo   = (const float*)d_in[2];   // (1024, 1024) fp32
    float* out = (float*)d_out;                  // (4096, 1024) fp32

    char* ws = (char*)d_ws;
    u16* xb    = (u16*)(ws + 0);                    // 4096x1024  (8 MB)
    u16* WqkvT = (u16*)(ws + (8u  << 20));          // 3072x1024  (6 MB)
    u16* WoT   = (u16*)(ws + (14u << 20));          // 1024x1024  (2 MB)
    u16* Qb    = (u16*)(ws + (16u << 20));          // (B,H,T,64) (8 MB)
    u16* Kb    = (u16*)(ws + (24u << 20));          // (B,H,T,64) (8 MB)
    u16* Vt    = (u16*)(ws + (32u << 20));          // (B,H,64,T) (8 MB)
    u16* attn  = (u16*)(ws + (40u << 20));          // (B,T,C)    (8 MB)

    prep_kernel<<<3072, 256, 0, stream>>>(x, xb, Wqkv, WqkvT, Wo, WoT);

    // qkv = x @ W_qkv (3-deep pipelined, 128x128): grid 768 = 3 blocks/CU.
    gemm_db<1, 128, 128, 24><<<768, 256, 0, stream>>>(
        xb, WqkvT, Qb, Kb, Vt, nullptr, BT, 3072, CD);

    // attn: 2048 2-wave blocks (32 q-rows), 8 blocks/CU, longest-first.
    attn_kernel<<<2048, 128, 0, stream>>>(Qb, Kb, Vt, attn);

    // out = attn @ W_o (3-deep pipelined, 64x64): grid 1024 = 4 blocks/CU.
    gemm_db<0, 64, 64, 16><<<1024, 256, 0, stream>>>(
        attn, WoT, nullptr, nullptr, nullptr, out, BT, CD, CD);
}

// Round 12
// 175.312 us; speedup vs baseline: 1.0337x; 1.0337x over previous
//
#include <hip/hip_runtime.h>

typedef unsigned short u16;
typedef unsigned int u32;
typedef __bf16 bf16x8 __attribute__((ext_vector_type(8)));
typedef float f32x4 __attribute__((ext_vector_type(4)));

#define DEV __device__ __forceinline__

// Problem constants (B,T,D_MODEL,H) = (2,2048,1024,16)
constexpr int BB = 2;
constexpr int TT = 2048;
constexpr int CD = 1024;
constexpr int HH = 16;
constexpr int DH = 64;
constexpr int BT = BB * TT;   // 4096

// softmax scale 1/8 folded with log2(e): S' = S/8*log2e, exp(x)=exp2(x')
#define QSCALE 0.18033688011112042f

// Native bf16 convert (RTNE): compiler packs pairs into v_cvt_pk_bf16_f32.
DEV u16 f2bf(float f) {
    return __builtin_bit_cast(u16, (__bf16)f);
}

DEV f32x4 mfma16(bf16x8 a, bf16x8 b, f32x4 c) {
    return __builtin_amdgcn_mfma_f32_16x16x32_bf16(a, b, c, 0, 0, 0);
}

// Async global->LDS, 16B per lane: LDS dest = wave-uniform base + lane*16.
DEV void gld_lds16(u16* lds, const u16* g) {
    __builtin_amdgcn_global_load_lds(
        (const __attribute__((address_space(1))) unsigned int*)g,
        (__attribute__((address_space(3))) unsigned int*)lds, 16, 0, 0);
}

// ---------------------------------------------------------------------------
// Fused preprocessing (single launch):
//   blocks [0,2048):      x fp32 -> bf16 (4096x1024), uint4-vectorized
//   blocks [2048,2816):   W_qkv (1024x3072) -> transposed bf16, 64x64 tiles
//   blocks [2816,3072):   W_o   (1024x1024) -> transposed bf16, 64x64 tiles
// ---------------------------------------------------------------------------
__global__ __launch_bounds__(256)
void prep_kernel(const float* __restrict__ x, u16* __restrict__ xb,
                 const float* __restrict__ Wqkv, u16* __restrict__ WqkvT,
                 const float* __restrict__ Wo, u16* __restrict__ WoT) {
    const int tid = threadIdx.x;
    int blk = blockIdx.x;
    if (blk < 2048) {                       // convert job
        const int i = (blk * 256 + tid) * 8;
        float4 a = *(const float4*)&x[i];
        float4 b = *(const float4*)&x[i + 4];
        u16 t[8];
        t[0] = f2bf(a.x); t[1] = f2bf(a.y); t[2] = f2bf(a.z); t[3] = f2bf(a.w);
        t[4] = f2bf(b.x); t[5] = f2bf(b.y); t[6] = f2bf(b.z); t[7] = f2bf(b.w);
        *(uint4*)&xb[i] = *(const uint4*)t;
        return;                             // whole block exits (no barrier)
    }
    __shared__ u16 tile[64][72];            // [col][row], padded stride
    const float* in; u16* out; int rows, cols, bx, by;
    blk -= 2048;
    if (blk < 768) { in = Wqkv; out = WqkvT; rows = 1024; cols = 3072; bx = blk % 48; by = blk / 48; }
    else { blk -= 768; in = Wo; out = WoT; rows = 1024; cols = 1024; bx = blk % 16; by = blk / 16; }
    const int c0 = bx * 64, r0 = by * 64;

    // read: 16 rows x 16 float4-groups per pass, 4 passes
    const int tx = tid & 15, ty = tid >> 4;
    #pragma unroll
    for (int p = 0; p < 4; ++p) {
        const int r = ty + p * 16;
        float4 v = *(const float4*)&in[(size_t)(r0 + r) * cols + c0 + tx * 4];
        tile[tx * 4 + 0][r] = f2bf(v.x);
        tile[tx * 4 + 1][r] = f2bf(v.y);
        tile[tx * 4 + 2][r] = f2bf(v.z);
        tile[tx * 4 + 3][r] = f2bf(v.w);
    }
    __syncthreads();

    // write: thread -> out-row c0+(tid>>2), 16 consecutive r at (tid&3)*16
    const int c = tid >> 2, r8 = (tid & 3) * 16;
    u16* dst = &out[(size_t)(c0 + c) * rows + r0 + r8];
    *(uint4*)dst       = *(const uint4*)&tile[c][r8];
    *(uint4*)(dst + 8) = *(const uint4*)&tile[c][r8 + 8];
}

// ---------------------------------------------------------------------------
// GEMM v4: 3-deep pipelined staging + counted vmcnt (T4) + chunk-XOR LDS
// swizzle (T2).  C[M][N] = A[M][K] * Bt[N][K]^T, bf16->fp32 acc.
// QKV = 128x128 (768 blocks, 3/CU); out-proj = 64x64 (1024 blocks, 4/CU).
// T1 XCD-chunked block swizzle.  (Unchanged from round 9/10.)
// ---------------------------------------------------------------------------
template <int EPI, int BM, int BN, int GX>
__global__ __launch_bounds__(256)
void gemm_db(const u16* __restrict__ A, const u16* __restrict__ Bt,
             u16* __restrict__ out0, u16* __restrict__ out1,
             u16* __restrict__ out2, float* __restrict__ outf,
             int M, int N, int K) {
    constexpr int BK = 32, AST = 32;
    constexpr int MT = BM / 32;             // m-tiles per wave
    constexpr int NT = BN / 32;             // n-tiles per wave
    constexpr int MBLK = 4096 / BM;         // M = 4096 always here
    constexpr int NBLK = GX * MBLK;
    constexpr int CPX = NBLK / 8;           // blocks per XCD chunk
    constexpr int LPS = BM / 64 + BN / 64;  // gld_lds per stage per wave
    __shared__ alignas(16) u16 As[3][BM * AST];
    __shared__ alignas(16) u16 Bs[3][BN * AST];

    const int tid  = threadIdx.x;
    const int wave = tid >> 6, lane = tid & 63;
    const int quad = lane >> 4, l16 = lane & 15;
    const int wm = (wave & 1) * (BM / 2), wn = (wave >> 1) * (BN / 2);

    // T1: XCD-aware chunked swizzle (bijective since NBLK % 8 == 0)
    int bid = (int)blockIdx.x;
    bid = (bid & 7) * CPX + (bid >> 3);
    const int bx = bid % GX, by = bid / GX;
    const int m0 = by * BM, n0 = bx * BN;

    // DMA staging: one instr = 64 lanes x 16B = 16 rows x 64B.
    // T2 pre-swizzled global source chunk (stored[r][c]=logical[c^((r>>1)&3)]).
    const int srowA = wave * (BM / 4) + (lane >> 2);
    const int srowB = wave * (BN / 4) + (lane >> 2);
    const int scol  = (((lane & 3) ^ ((lane >> 3) & 3))) * 8;
    const u16* ga0 = A  + (size_t)(m0 + srowA) * K + scol;
    const u16* ga1 = ga0 + (size_t)16 * K;
    const u16* gb0 = Bt + (size_t)(n0 + srowB) * K + scol;
    const u16* gb1 = gb0 + (size_t)16 * K;

    auto stage = [&](int buf, int k0) {
        gld_lds16(&As[buf][wave * (BM / 4) * 32],       ga0 + k0);
        if constexpr (BM == 128)
            gld_lds16(&As[buf][wave * (BM / 4) * 32 + 512], ga1 + k0);
        gld_lds16(&Bs[buf][wave * (BN / 4) * 32],       gb0 + k0);
        if constexpr (BN == 128)
            gld_lds16(&Bs[buf][wave * (BN / 4) * 32 + 512], gb1 + k0);
    };
    // mid-loop counted wait: one stage (LPS loads) stays in flight
    auto wait_lps = [&]() {
        if constexpr (LPS == 4)      asm volatile("s_waitcnt vmcnt(4)" ::: "memory");
        else if constexpr (LPS == 3) asm volatile("s_waitcnt vmcnt(3)" ::: "memory");
        else                         asm volatile("s_waitcnt vmcnt(2)" ::: "memory");
    };

    f32x4 acc[MT][NT] = {};

    stage(0, 0);
    stage(1, BK);
    wait_lps();                              // step-0 buffers landed
    __builtin_amdgcn_s_barrier();

    const int sx = ((l16 >> 1) & 3) * 8;     // T2 read-side XOR term
    const int NS = K / BK;
    int cb = 0;                              // current buffer
    for (int t = 0; t < NS; ++t) {
        const bool pf = (t + 2 < NS);
        int sb = cb + 2; if (sb >= 3) sb -= 3;
        if (pf) stage(sb, (t + 2) * BK);

        bf16x8 fa[MT], fb[NT];
        #pragma unroll
        for (int mt = 0; mt < MT; ++mt)
            fa[mt] = *(const bf16x8*)
                &As[cb][(wm + mt * 16 + l16) * AST + (quad * 8 ^ sx)];
        #pragma unroll
        for (int nt = 0; nt < NT; ++nt)
            fb[nt] = *(const bf16x8*)
                &Bs[cb][(wn + nt * 16 + l16) * AST + (quad * 8 ^ sx)];
        #pragma unroll
        for (int mt = 0; mt < MT; ++mt)
            #pragma unroll
            for (int nt = 0; nt < NT; ++nt)
                acc[mt][nt] = mfma16(fa[mt], fb[nt], acc[mt][nt]);

        if (pf) wait_lps();                  // drain stage for step t+1 only
        else    asm volatile("s_waitcnt vmcnt(0)" ::: "memory");
        __builtin_amdgcn_s_barrier();
        cb = (cb + 1 == 3) ? 0 : cb + 1;
    }

    // Epilogue. C/D layout: row = quad*4+reg, col = l16.
    #pragma unroll
    for (int mt = 0; mt < MT; ++mt) {
        #pragma unroll
        for (int nt = 0; nt < NT; ++nt) {
            #pragma unroll
            for (int reg = 0; reg < 4; ++reg) {
                const int r = m0 + wm + mt * 16 + quad * 4 + reg;
                const int c = n0 + wn + nt * 16 + l16;
                if (EPI == 0) {
                    outf[(size_t)r * N + c] = acc[mt][nt][reg];
                } else {
                    const int which = c >> 10;       // 0=q 1=k 2=v
                    const int cc = c & 1023;
                    const int h = cc >> 6, d = cc & 63;
                    const int b = r >> 11, t = r & 2047;
                    const int bh = b * HH + h;
                    if (which == 0) {
                        out0[((size_t)bh * TT + t) * DH + d] =
                            f2bf(acc[mt][nt][reg] * QSCALE);
                    } else if (which == 1) {
                        out1[((size_t)bh * TT + t) * DH + d] = f2bf(acc[mt][nt][reg]);
                    } else {
                        out2[((size_t)bh * DH + d) * TT + t] = f2bf(acc[mt][nt][reg]);
                    }
                }
            }
        }
    }
}

// ---------------------------------------------------------------------------
// Flash attention v10 (causal): v8 schedule (1024 single-q-tile blocks,
// 4 waves, double-buffered, longest-first, bh->XCD locality) + v9's
// K-staging via global_load_lds with XOR chunk swizzle:
//   K: Ks[2][64x64], DMA-staged; pre-swizzled global source chunk
//      (l&7)^(l>>3) -> stored[r][c] = logical[c^(r&7)]; fragment reads at
//      chunk (ks*4+quad)^(l16&7) -> 2 lanes/bank = conflict-free (m136).
//      Removes the K register round-trip (VALU + 8 VGPR) and the K-side
//      LDS bank conflicts (v8 measured 3.2M conflict-cycles/dispatch).
//   V: Vs[2][64xKST], reg-staged pair-permuted (permutation can't ride
//      gld_lds's linear lane->dest mapping).
// Schedule/step: sync (K-DMA drained by vmcnt(0), V writes visible) ->
//   kdma(j+1)+vload(j+1) [full compute phase of latency cover; target
//   buffer's readers finished before the barrier -> WAR-safe] ->
//   compute(j) -> vwrite(j+1).
// Keeps v8's ones-row l-accumulation + defer-max (measured win).
// v9 lesson: 2-wave/32-row blocks doubled total block-steps -- never
// trade per-step efficiency for occupancy here.
// ---------------------------------------------------------------------------
constexpr int KST = 72;  // V LDS row stride (144 B, rows 16B-aligned)

DEV void attn_step(const bf16x8 fk[4][2], const bf16x8 fv[2][4],
                   const bf16x8 fone, const bf16x8* fq,
                   f32x4* Oacc, f32x4& lacc, float& m_i, bool diag,
                   int wave, int quad, int l16) {
    // S^T: 4 key-tiles x 2 k-steps over d
    f32x4 st[4];
    #pragma unroll
    for (int nt = 0; nt < 4; ++nt) {
        f32x4 t = {};
        t = mfma16(fk[nt][0], fq[0], t);   // A=K (m=key), B=Q (n=q)
        t = mfma16(fk[nt][1], fq[1], t);
        st[nt] = t;
    }

    // causal mask on diagonal tile: key_loc <= q_loc
    if (diag) {
        const int qg = wave * 16 + l16;
        #pragma unroll
        for (int nt = 0; nt < 4; ++nt)
            #pragma unroll
            for (int reg = 0; reg < 4; ++reg) {
                const int kg = nt * 16 + quad * 4 + reg;
                st[nt][reg] = (kg <= qg) ? st[nt][reg] : -INFINITY;
            }
    }

    // row max: depth-4 tree + 2 cross-quad shuffles (lane = quad*16+l16)
    float v[16];
    #pragma unroll
    for (int nt = 0; nt < 4; ++nt)
        #pragma unroll
        for (int reg = 0; reg < 4; ++reg)
            v[nt * 4 + reg] = st[nt][reg];
    #pragma unroll
    for (int s = 8; s > 0; s >>= 1)
        #pragma unroll
        for (int i = 0; i < s; ++i)
            v[i] = fmaxf(v[i], v[i + s]);
    float vmax = v[0];
    vmax = fmaxf(vmax, __shfl_xor(vmax, 16, 64));
    vmax = fmaxf(vmax, __shfl_xor(vmax, 32, 64));

    // defer-max: rescale only when some row's max grew past THR=8 (exp2 dom)
    if (!__all(vmax - m_i <= 8.f)) {
        const float mnew = fmaxf(m_i, vmax);
        const float alpha = __builtin_amdgcn_exp2f(m_i - mnew);
        m_i = mnew;
        #pragma unroll
        for (int dt = 0; dt < 4; ++dt)
            #pragma unroll
            for (int reg = 0; reg < 4; ++reg)
                Oacc[dt][reg] *= alpha;
        #pragma unroll
        for (int reg = 0; reg < 4; ++reg)
            lacc[reg] *= alpha;
    }

    #pragma unroll
    for (int nt = 0; nt < 4; ++nt)
        #pragma unroll
        for (int reg = 0; reg < 4; ++reg)
            st[nt][reg] = __builtin_amdgcn_exp2f(st[nt][reg] - m_i);

    // P^T B-operand: reg j<4 = st[2p][j] (key p*32+quad*4+j),
    //                reg j>=4 = st[2p+1][j-4] (key p*32+16+quad*4+j-4)
    // ones-row MFMA accumulates sum(P) into lacc (C row 0 = quad0/reg0).
    #pragma unroll
    for (int pair = 0; pair < 2; ++pair) {
        bf16x8 pb;
        #pragma unroll
        for (int j = 0; j < 4; ++j) {
            pb[j]     = (__bf16)st[2 * pair][j];
            pb[4 + j] = (__bf16)st[2 * pair + 1][j];
        }
        lacc = mfma16(fone, pb, lacc);
        #pragma unroll
        for (int dt = 0; dt < 4; ++dt)
            Oacc[dt] = mfma16(fv[pair][dt], pb, Oacc[dt]);
    }
}

__global__ __launch_bounds__(256, 4)
void attn_kernel(const u16* __restrict__ Q, const u16* __restrict__ Kb,
                 const u16* __restrict__ Vt, u16* __restrict__ O) {
    __shared__ alignas(16) u16 Ks[2][64 * 64];   // K, chunk-XOR swizzled
    __shared__ alignas(16) u16 Vs[2][64 * KST];  // V, pair-permuted

    // Decode: bid[2:0]=xcd (hosts bh with bh&7==xcd), bid[4:3]=bh>>3,
    // bid[9:5]=31-qt (longest q-tile dispatched first).
    const int bid = (int)blockIdx.x;
    const int j2 = bid >> 3;
    const int qt = 31 - (j2 >> 2);
    const int bh = (bid & 7) + 8 * (j2 & 3);
    const int jmax = qt;

    const int tid = threadIdx.x;
    const int wave = tid >> 6, lane = tid & 63;
    const int quad = lane >> 4, l16 = lane & 15;

    const u16* Qh = Q  + (size_t)bh * TT * DH;
    const u16* Kh = Kb + (size_t)bh * TT * DH;
    const u16* Vh = Vt + (size_t)bh * DH * TT;

    const int row = qt * 64 + wave * 16;

    // Q fragments (B-operand: n = l16 = q, k = quad*8+j over d)
    bf16x8 fq[2];
    fq[0] = *(const bf16x8*)&Qh[(row + l16) * DH + quad * 8];
    fq[1] = *(const bf16x8*)&Qh[(row + l16) * DH + 32 + quad * 8];

    // ones A-fragment: lanes with l16==0 hold the all-ones row 0.
    bf16x8 fone;
    {
        const __bf16 ov = (l16 == 0) ? (__bf16)1.f : (__bf16)0.f;
        #pragma unroll
        for (int j = 0; j < 8; ++j) fone[j] = ov;
    }

    f32x4 Oa[4] = {}, lacc = {};
    float m_i = -INFINITY;

    // K DMA: per wave 2x gld_lds, each covers 8 rows x 128 B (16 rows/wave).
    // Lane l writes LDS row base+(l>>3), chunk (l&7); source fetches logical
    // chunk (l&7)^(l>>3) so stored[r][c] = logical[c^(r&7)]  (bases % 8 == 0).
    const int krow8  = lane >> 3;                       // 0..7
    const int kchunk = ((lane & 7) ^ krow8) * 8;
    const u16* gK = Kh + (size_t)(wave * 16 + krow8) * DH + kchunk;
    auto kdma = [&](int j, int buf) {
        const u16* g = gK + (size_t)j * 64 * DH;
        gld_lds16(&Ks[buf][(wave * 16) * 64],     g);
        gld_lds16(&Ks[buf][(wave * 16 + 8) * 64], g + (size_t)8 * DH);
    };

    // V staging: thread i covers 16B at row (i>>3), col (i&7)*8, +row32,
    // written at pair-permuted columns (fragments become one b128).
    const int trow = tid >> 3;               // 0..31
    const int ic   = tid & 7;                // 8-key group index
    const int tcol = ic * 8;
    const int vc1 = 32 * (ic >> 2) + 16 * (ic & 1) + 4 * ((ic & 3) >> 1);
    uint4 vr0, vr1;

    auto vload = [&](int j) {
        const u16* vs = Vh + (size_t)j * 64;
        vr0 = *(const uint4*)&vs[(size_t)trow * TT + tcol];
        vr1 = *(const uint4*)&vs[(size_t)(trow + 32) * TT + tcol];
    };
    auto vwrite = [&](int buf) {
        *(uint2*)&Vs[buf][trow * KST + vc1]            = *(const uint2*)&vr0;
        *(uint2*)&Vs[buf][trow * KST + vc1 + 8]        = *((const uint2*)&vr0 + 1);
        *(uint2*)&Vs[buf][(trow + 32) * KST + vc1]     = *(const uint2*)&vr1;
        *(uint2*)&Vs[buf][(trow + 32) * KST + vc1 + 8] = *((const uint2*)&vr1 + 1);
    };

    kdma(0, 0);
    vload(0);
    vwrite(0);                               // data dep drains vmcnt incl. kdma

    for (int j = 0; j <= jmax; ++j) {
        const int cur = j & 1;
        __syncthreads();                     // K[cur] landed (vmcnt), V[cur] visible
        if (j < jmax) {                      // next chunk flies during compute;
            kdma(j + 1, cur ^ 1);            // buf^1 readers done before barrier
            vload(j + 1);
        }

        // K fragments: logical chunk ks*4+quad at row r -> phys ^ (l16&7)
        bf16x8 fk[4][2], fv[2][4];
        #pragma unroll
        for (int nt = 0; nt < 4; ++nt)
            #pragma unroll
            for (int ks = 0; ks < 2; ++ks)
                fk[nt][ks] = *(const bf16x8*)
                    &Ks[cur][(nt * 16 + l16) * 64 + (((ks * 4 + quad) ^ (l16 & 7)) << 3)];
        #pragma unroll
        for (int pair = 0; pair < 2; ++pair)
            #pragma unroll
            for (int dt = 0; dt < 4; ++dt)
                fv[pair][dt] = *(const bf16x8*)
                    &Vs[cur][(dt * 16 + l16) * KST + pair * 32 + quad * 8];

        attn_step(fk, fv, fone, fq, Oa, lacc, m_i, (j == qt),
                  wave, quad, l16);
        if (j < jmax) vwrite(cur ^ 1);       // after all buf[cur^1] readers done
    }

    // l for this lane's q-col lives in the quad-0 lane of the same column.
    const float lrow = __shfl(lacc[0], l16, 64);
    const float r_i = 1.f / lrow;

    // Epilogue: O^T rows d = dt*16+quad*4+reg, col q = l16; write (B,T,C).
    const int b = bh >> 4, h = bh & 15;
    #pragma unroll
    for (int dt = 0; dt < 4; ++dt) {
        u16 oa[4];
        #pragma unroll
        for (int reg = 0; reg < 4; ++reg)
            oa[reg] = f2bf(Oa[dt][reg] * r_i);
        *(uint2*)&O[((size_t)(b * TT + row + l16)) * CD + h * DH + dt * 16 + quad * 4] =
            *(const uint2*)oa;
    }
}

// ---------------------------------------------------------------------------
extern "C" void kernel_launch(void* const* d_in, const int* in_sizes, int n_in,
                              void* d_out, int out_size, void* d_ws, size_t ws_size,
                              hipStream_t stream) {
    (void)in_sizes; (void)n_in; (void)out_size; (void)ws_size;
    const float* x    = (const float*)d_in[0];   // (4096, 1024) fp32
    const float* Wqkv = (const float*)d_in[1];   // (1024, 3072) fp32
    const float* Wo   = (const float*)d_in[2];   // (1024, 1024) fp32
    float* out = (float*)d_out;                  // (4096, 1024) fp32

    char* ws = (char*)d_ws;
    u16* xb    = (u16*)(ws + 0);                    // 4096x1024  (8 MB)
    u16* WqkvT = (u16*)(ws + (8u  << 20));          // 3072x1024  (6 MB)
    u16* WoT   = (u16*)(ws + (14u << 20));          // 1024x1024  (2 MB)
    u16* Qb    = (u16*)(ws + (16u << 20));          // (B,H,T,64) (8 MB)
    u16* Kb    = (u16*)(ws + (24u << 20));          // (B,H,T,64) (8 MB)
    u16* Vt    = (u16*)(ws + (32u << 20));          // (B,H,64,T) (8 MB)
    u16* attn  = (u16*)(ws + (40u << 20));          // (B,T,C)    (8 MB)

    prep_kernel<<<3072, 256, 0, stream>>>(x, xb, Wqkv, WqkvT, Wo, WoT);

    // qkv = x @ W_qkv (3-deep pipelined, 128x128): grid 768 = 3 blocks/CU.
    gemm_db<1, 128, 128, 24><<<768, 256, 0, stream>>>(
        xb, WqkvT, Qb, Kb, Vt, nullptr, BT, 3072, CD);

    // attn: 1024 single-q-tile blocks (4 waves), longest-first, XCD-local.
    attn_kernel<<<1024, 256, 0, stream>>>(Qb, Kb, Vt, attn);

    // out = attn @ W_o (3-deep pipelined, 64x64): grid 1024 = 4 blocks/CU.
    gemm_db<0, 64, 64, 16><<<1024, 256, 0, stream>>>(
        attn, WoT, nullptr, nullptr, nullptr, out, BT, CD, CD);
}